// Round 2
// 244.397 us; speedup vs baseline: 1.1271x; 1.1271x over previous
//
#include <hip/hip_runtime.h>

#define Bc 1024
#define Tc 512
#define Ic 64
#define Hc 32
#define XP 516   // xq row pitch (bf16): 8B-aligned rows, dw-pitch 258 -> 2-way banks
#define LOG2E2 2.8853900817779268f   // 2*log2(e): tanh(a) = 1 - 2/(2^(a*LOG2E2)+1)

typedef __bf16 bf16x8 __attribute__((ext_vector_type(8)));
typedef __bf16 bf16x4 __attribute__((ext_vector_type(4)));
typedef float  f32x4  __attribute__((ext_vector_type(4)));

__device__ inline bf16x8 to_bf16x8(float4 u0, float4 u1) {
    bf16x8 t;
    t[0] = (__bf16)u0.x; t[1] = (__bf16)u0.y; t[2] = (__bf16)u0.z; t[3] = (__bf16)u0.w;
    t[4] = (__bf16)u1.x; t[5] = (__bf16)u1.y; t[6] = (__bf16)u1.z; t[7] = (__bf16)u1.w;
    return t;
}
__device__ inline bf16x8 to_bf16x8s(float4 u0, float4 u1, float s) {
    bf16x8 t;
    t[0] = (__bf16)(u0.x*s); t[1] = (__bf16)(u0.y*s); t[2] = (__bf16)(u0.z*s); t[3] = (__bf16)(u0.w*s);
    t[4] = (__bf16)(u1.x*s); t[5] = (__bf16)(u1.y*s); t[6] = (__bf16)(u1.z*s); t[7] = (__bf16)(u1.w*s);
    return t;
}

// ---------------------------------------------------------------------------
// R8 (resubmit; R1 bench was a container-acquisition failure, not a kernel
// failure): latency-chain surgery on the scan + phase-1 fused into the loop.
//  - recurrent state broadcast as packed f16 r=1/(e^{2a}+1): 4x ds_read_b128
//    (was 8x with f32 h); consumed via v_fma_mix_f32 (f16 x f32 + f32, exact).
//  - tanh affine folded into weights: W' = -2*Whh, bias' = bhh + rowsum(Whh);
//    2*log2e pre-scaled into Wih/bih/W'/bias' so exp2 needs no multiply.
//  - x-projection tiles (MFMA, R7-verified layout) computed inside the scan
//    loop, 2 tile-pairs ahead; global x loads issued 3 pairs ahead (~8k cyc
//    of slack). Removes the ~15us serial phase-1 prologue.
// Block = 1 wave, 2 batches (half-wave each); all 512 blocks co-resident, so
// wall-clock = 512 * per-step chain latency. This round shortens the chain.
// ---------------------------------------------------------------------------

#define FMIX_LO(acc, hw, wf)                                                  \
    asm("v_fma_mix_f32 %0, %1, %2, %0 op_sel:[0,0,0] op_sel_hi:[1,0,0]"       \
        : "+v"(acc) : "v"(hw), "v"(wf));
#define FMIX_HI(acc, hw, wf)                                                  \
    asm("v_fma_mix_f32 %0, %1, %2, %0 op_sel:[1,0,0] op_sel_hi:[1,0,0]"       \
        : "+v"(acc) : "v"(hw), "v"(wf));

#define STEP(xval, uu)                                                        \
    {                                                                         \
        hbuf[half][h] = rv;                                                   \
        __builtin_amdgcn_wave_barrier();                                      \
        const uint4 Ha = hq[0], Hb = hq[1], Hc2 = hq[2], Hd2 = hq[3];         \
        float a0 = (xval) + biasc, a1 = 0.f, a2 = 0.f, a3 = 0.f;              \
        FMIX_LO(a0, Ha.x, w0.x)  FMIX_HI(a1, Ha.x, w0.y)                      \
        FMIX_LO(a2, Ha.y, w0.z)  FMIX_HI(a3, Ha.y, w0.w)                      \
        FMIX_LO(a0, Ha.z, w1.x)  FMIX_HI(a1, Ha.z, w1.y)                      \
        FMIX_LO(a2, Ha.w, w1.z)  FMIX_HI(a3, Ha.w, w1.w)                      \
        FMIX_LO(a0, Hb.x, w2.x)  FMIX_HI(a1, Hb.x, w2.y)                      \
        FMIX_LO(a2, Hb.y, w2.z)  FMIX_HI(a3, Hb.y, w2.w)                      \
        FMIX_LO(a0, Hb.z, w3.x)  FMIX_HI(a1, Hb.z, w3.y)                      \
        FMIX_LO(a2, Hb.w, w3.z)  FMIX_HI(a3, Hb.w, w3.w)                      \
        FMIX_LO(a0, Hc2.x, w4.x) FMIX_HI(a1, Hc2.x, w4.y)                     \
        FMIX_LO(a2, Hc2.y, w4.z) FMIX_HI(a3, Hc2.y, w4.w)                     \
        FMIX_LO(a0, Hc2.z, w5.x) FMIX_HI(a1, Hc2.z, w5.y)                     \
        FMIX_LO(a2, Hc2.w, w5.z) FMIX_HI(a3, Hc2.w, w5.w)                     \
        FMIX_LO(a0, Hd2.x, w6.x) FMIX_HI(a1, Hd2.x, w6.y)                     \
        FMIX_LO(a2, Hd2.y, w6.z) FMIX_HI(a3, Hd2.y, w6.w)                     \
        FMIX_LO(a0, Hd2.z, w7.x) FMIX_HI(a1, Hd2.z, w7.y)                     \
        FMIX_LO(a2, Hd2.w, w7.z) FMIX_HI(a3, Hd2.w, w7.w)                     \
        const float a_ = (a0 + a1) + (a2 + a3);                               \
        const float p_ = __builtin_amdgcn_exp2f(a_);                          \
        rr = __builtin_amdgcn_rcpf(p_ + 1.0f);                                \
        rv = (_Float16)rr;                                                    \
        pbuf[half][uu][h] = fmaf(rr, w2o, wo);                                \
        __builtin_amdgcn_wave_barrier();                                      \
    }

// convert bf16x4 -> float4 (widening, exact)
#define CVT4(dst, src)                                                        \
    dst.x = (float)(src)[0]; dst.y = (float)(src)[1];                         \
    dst.z = (float)(src)[2]; dst.w = (float)(src)[3];

// phase-1 tile: global loads -> regs (issued ~1 block ahead of use)
#define TILE_LOAD(Xn, bb, lt)                                                 \
    do {                                                                      \
        const float* xp_ =                                                    \
            x + ((size_t)(b0 + (bb)) * Tc + (lt) * 16 + m) * Ic + q * 8;      \
        Xn##0 = ((const float4*)xp_)[0];                                      \
        Xn##1 = ((const float4*)xp_)[1];                                      \
        Xn##2 = ((const float4*)(xp_ + 32))[0];                               \
        Xn##3 = ((const float4*)(xp_ + 32))[1];                               \
    } while (0)

// phase-1 tile: MFMA + bias + bf16 pack + LDS store (R7-verified D layout:
// col=lane&15 -> h, row=q*4+reg -> t)
#define TILE_MFMA(Xn, bb, lt)                                                 \
    do {                                                                      \
        const bf16x8 A0_ = to_bf16x8(Xn##0, Xn##1);                           \
        const bf16x8 A1_ = to_bf16x8(Xn##2, Xn##3);                           \
        f32x4 ac0 = {0.f, 0.f, 0.f, 0.f};                                     \
        f32x4 ac1 = {0.f, 0.f, 0.f, 0.f};                                     \
        ac0 = __builtin_amdgcn_mfma_f32_16x16x32_bf16(A0_, Bf[0][0], ac0, 0, 0, 0); \
        ac0 = __builtin_amdgcn_mfma_f32_16x16x32_bf16(A1_, Bf[0][1], ac0, 0, 0, 0); \
        ac1 = __builtin_amdgcn_mfma_f32_16x16x32_bf16(A0_, Bf[1][0], ac1, 0, 0, 0); \
        ac1 = __builtin_amdgcn_mfma_f32_16x16x32_bf16(A1_, Bf[1][1], ac1, 0, 0, 0); \
        bf16x4 p0_, p1_;                                                      \
        p0_[0] = (__bf16)(ac0[0] + bias0); p0_[1] = (__bf16)(ac0[1] + bias0); \
        p0_[2] = (__bf16)(ac0[2] + bias0); p0_[3] = (__bf16)(ac0[3] + bias0); \
        p1_[0] = (__bf16)(ac1[0] + bias1); p1_[1] = (__bf16)(ac1[1] + bias1); \
        p1_[2] = (__bf16)(ac1[2] + bias1); p1_[3] = (__bf16)(ac1[3] + bias1); \
        *(bf16x4*)&xq[bb][m][(lt) * 16 + q * 4]      = p0_;                   \
        *(bf16x4*)&xq[bb][m + 16][(lt) * 16 + q * 4] = p1_;                   \
    } while (0)

__global__ __launch_bounds__(64) void fused_rnn_kernel(
    const float* __restrict__ x, const float* __restrict__ Wih,
    const float* __restrict__ bih, const float* __restrict__ h0,
    const float* __restrict__ Whh, const float* __restrict__ bhh,
    const float* __restrict__ Wout, const float* __restrict__ bout,
    float* __restrict__ out)
{
    __shared__ __bf16   xq[2][Hc][XP];    // 66048 B (scaled x-proj, bf16)
    __shared__ _Float16 hbuf[2][32];      // 128 B   (packed f16 r-state)
    __shared__ float    pbuf[2][16][34];  // 4352 B  -> ~69 KB, 2 blk/CU

    const int lane = threadIdx.x;
    const int half = lane >> 5;
    const int h    = lane & 31;
    const int m    = lane & 15;   // MFMA A-row / B-n index
    const int q    = lane >> 4;   // MFMA quad
    const int b0   = blockIdx.x * 2;

    // ---- init: Wih fragments (pre-scaled by LOG2E2), W' = -2*LOG2E2*Whh ----
    bf16x8 Bf[2][2];
#pragma unroll
    for (int nh = 0; nh < 2; ++nh)
#pragma unroll
        for (int kh = 0; kh < 2; ++kh) {
            const float* wp = Wih + (m + 16 * nh) * Ic + q * 8 + kh * 32;
            Bf[nh][kh] = to_bf16x8s(((const float4*)wp)[0],
                                    ((const float4*)wp)[1], LOG2E2);
        }
    const float bias0 = bih[m] * LOG2E2;
    const float bias1 = bih[m + 16] * LOG2E2;

    const float4* wrow = (const float4*)(Whh + h * Hc);
    float4 t0 = wrow[0], t1 = wrow[1], t2 = wrow[2], t3 = wrow[3],
           t4 = wrow[4], t5 = wrow[5], t6 = wrow[6], t7 = wrow[7];
    const float rsum =
        (((t0.x + t0.y) + (t0.z + t0.w)) + ((t1.x + t1.y) + (t1.z + t1.w))) +
        (((t2.x + t2.y) + (t2.z + t2.w)) + ((t3.x + t3.y) + (t3.z + t3.w))) +
        (((t4.x + t4.y) + (t4.z + t4.w)) + ((t5.x + t5.y) + (t5.z + t5.w))) +
        (((t6.x + t6.y) + (t6.z + t6.w)) + ((t7.x + t7.y) + (t7.z + t7.w)));
    const float cw = -2.0f * LOG2E2;
    float4 w0, w1, w2, w3, w4, w5, w6, w7;
    w0.x = t0.x*cw; w0.y = t0.y*cw; w0.z = t0.z*cw; w0.w = t0.w*cw;
    w1.x = t1.x*cw; w1.y = t1.y*cw; w1.z = t1.z*cw; w1.w = t1.w*cw;
    w2.x = t2.x*cw; w2.y = t2.y*cw; w2.z = t2.z*cw; w2.w = t2.w*cw;
    w3.x = t3.x*cw; w3.y = t3.y*cw; w3.z = t3.z*cw; w3.w = t3.w*cw;
    w4.x = t4.x*cw; w4.y = t4.y*cw; w4.z = t4.z*cw; w4.w = t4.w*cw;
    w5.x = t5.x*cw; w5.y = t5.y*cw; w5.z = t5.z*cw; w5.w = t5.w*cw;
    w6.x = t6.x*cw; w6.y = t6.y*cw; w6.z = t6.z*cw; w6.w = t6.w*cw;
    w7.x = t7.x*cw; w7.y = t7.y*cw; w7.z = t7.z*cw; w7.w = t7.w*cw;
    const float biasc = (bhh[h] + rsum) * LOG2E2;  // bias' (pre-scaled)
    const float wo  = Wout[h];
    const float w2o = -2.0f * wo;
    const float bo  = bout[0];

    // r = (1 - h)/2; h0 is the initial hidden state
    float rr = fmaf(-0.5f, h0[(size_t)(b0 + half) * Hc + h], 0.5f);
    _Float16 rv = (_Float16)rr;
    float* orow = out + (size_t)(b0 + half) * Tc;

    // ---- phase-1 prologue: tile-pairs 0,1 direct; stage pair-2 loads ------
    float4 Xa0, Xa1, Xa2, Xa3, Xb0, Xb1, Xb2, Xb3;
    TILE_LOAD(Xa, 0, 0);  TILE_LOAD(Xb, 1, 0);
    TILE_MFMA(Xa, 0, 0);  TILE_MFMA(Xb, 1, 0);
    TILE_LOAD(Xa, 0, 1);  TILE_LOAD(Xb, 1, 1);
    TILE_MFMA(Xa, 0, 1);  TILE_MFMA(Xb, 1, 1);
    TILE_LOAD(Xa, 0, 2);  TILE_LOAD(Xb, 1, 2);
    __builtin_amdgcn_wave_barrier();

    // ---- scan ----
    const __bf16* xrow = &xq[half][h][0];
    const uint4*  hq   = (const uint4*)&hbuf[half][0];

    bf16x4 r0 = *(const bf16x4*)(xrow + 0), r1 = *(const bf16x4*)(xrow + 4),
           r2 = *(const bf16x4*)(xrow + 8), r3 = *(const bf16x4*)(xrow + 12);
    float4 q0, q1, q2, q3;
    CVT4(q0, r0) CVT4(q1, r1) CVT4(q2, r2) CVT4(q3, r3)

#pragma unroll 1
    for (int tb = 0; tb < Tc / 16; ++tb) {
        const int tbn = (tb + 1 < Tc / 16) ? tb + 1 : tb;
        const __bf16* nx = xrow + tbn * 16;
        const bf16x4 m0 = *(const bf16x4*)(nx + 0),
                     m1 = *(const bf16x4*)(nx + 4),
                     m2 = *(const bf16x4*)(nx + 8),
                     m3 = *(const bf16x4*)(nx + 12);

        // fused phase-1: compute pair tb+2 (regs loaded last block), then
        // issue global loads for pair tb+3 (consumed next block).
        if (tb + 2 < Tc / 16) { TILE_MFMA(Xa, 0, tb + 2); TILE_MFMA(Xb, 1, tb + 2); }
        if (tb + 3 < Tc / 16) { TILE_LOAD(Xa, 0, tb + 3); TILE_LOAD(Xb, 1, tb + 3); }

        STEP(q0.x, 0)  STEP(q0.y, 1)  STEP(q0.z, 2)  STEP(q0.w, 3)
        STEP(q1.x, 4)  STEP(q1.y, 5)  STEP(q1.z, 6)  STEP(q1.w, 7)
        STEP(q2.x, 8)  STEP(q2.y, 9)  STEP(q2.z, 10) STEP(q2.w, 11)
        STEP(q3.x, 12) STEP(q3.y, 13) STEP(q3.z, 14) STEP(q3.w, 15)

        __builtin_amdgcn_wave_barrier();

        // both halves reduce their own batch; coalesced 16-wide stores
        if (h < 16) {
            const float2* pr = (const float2*)pbuf[half][h];
            float2 sa = pr[0], sb = pr[1];
#pragma unroll
            for (int mm = 2; mm < 16; mm += 2) {
                sa.x += pr[mm].x;     sa.y += pr[mm].y;
                sb.x += pr[mm + 1].x; sb.y += pr[mm + 1].y;
            }
            orow[tb * 16 + h] = ((sa.x + sb.x) + (sa.y + sb.y)) + bo;
        }
        __builtin_amdgcn_wave_barrier();

        CVT4(q0, m0) CVT4(q1, m1) CVT4(q2, m2) CVT4(q3, m3)
    }

    // h_last: [1, B, H] appended after outs [B, T, 1]; h = 1 - 2r
    out[(size_t)Bc * Tc + (size_t)(b0 + half) * Hc + h] = fmaf(-2.0f, rr, 1.0f);
}

extern "C" void kernel_launch(void* const* d_in, const int* in_sizes, int n_in,
                              void* d_out, int out_size, void* d_ws, size_t ws_size,
                              hipStream_t stream) {
    const float* x    = (const float*)d_in[0];
    const float* h0   = (const float*)d_in[1];
    const float* Wih  = (const float*)d_in[2];
    const float* bih  = (const float*)d_in[3];
    const float* Whh  = (const float*)d_in[4];
    const float* bhh  = (const float*)d_in[5];
    const float* Wout = (const float*)d_in[6];
    const float* bout = (const float*)d_in[7];
    float* out = (float*)d_out;

    fused_rnn_kernel<<<Bc / 2, 64, 0, stream>>>(x, Wih, bih, h0, Whh, bhh,
                                                Wout, bout, out);
}

// Round 3
// 229.133 us; speedup vs baseline: 1.2022x; 1.0666x over previous
//
#include <hip/hip_runtime.h>

#define Bc 1024
#define Tc 512
#define Ic 64
#define Hc 32
#define XP 516   // xq row pitch (bf16): 8B-aligned rows, dw-pitch 258 -> 2-way banks
#define LOG2E2 2.8853900817779268f   // 2*log2(e): tanh(a) = 1 - 2/(2^(a*LOG2E2)+1)

typedef __bf16 bf16x8 __attribute__((ext_vector_type(8)));
typedef __bf16 bf16x4 __attribute__((ext_vector_type(4)));
typedef float  f32x4  __attribute__((ext_vector_type(4)));
typedef _Float16 half2v __attribute__((ext_vector_type(2)));
typedef unsigned uint2v __attribute__((ext_vector_type(2)));

__device__ inline bf16x8 to_bf16x8(float4 u0, float4 u1) {
    bf16x8 t;
    t[0] = (__bf16)u0.x; t[1] = (__bf16)u0.y; t[2] = (__bf16)u0.z; t[3] = (__bf16)u0.w;
    t[4] = (__bf16)u1.x; t[5] = (__bf16)u1.y; t[6] = (__bf16)u1.z; t[7] = (__bf16)u1.w;
    return t;
}
__device__ inline bf16x8 to_bf16x8s(float4 u0, float4 u1, float s) {
    bf16x8 t;
    t[0] = (__bf16)(u0.x*s); t[1] = (__bf16)(u0.y*s); t[2] = (__bf16)(u0.z*s); t[3] = (__bf16)(u0.w*s);
    t[4] = (__bf16)(u1.x*s); t[5] = (__bf16)(u1.y*s); t[6] = (__bf16)(u1.z*s); t[7] = (__bf16)(u1.w*s);
    return t;
}

// ---------------------------------------------------------------------------
// R9: replace the per-step LDS broadcast round-trip (~150-200 cyc serial:
// ds_write + lgkmcnt + 4x ds_read_b128) with an in-register 32-lane all-gather
// butterfly (~35 cyc): permlane16_swap (^16) then DPP row_ror 8/4/2/1
// rotation-doubling (covers all 16 row positions; stays within 32-lane
// halves so the two batches never mix). Values arrive lane-scrambled; each
// lane's Whh row is pre-permuted at init by running the IDENTICAL butterfly
// on integer h-indices (also discovers swap direction empirically -> psel).
// Gathered f16 pairs consumed by v_dot2_f32_f16 (16 dots, f32 accum, exact
// f16 products). Weights f16 (4.9e-4 rel, ~8x below bf16-xq error).
// Phase-1 MFMA x-projection fused in the scan loop (R8, verified).
// ---------------------------------------------------------------------------

#if __has_builtin(__builtin_amdgcn_permlane16_swap)
#define PLSWAP(A, B)                                                          \
    { uint2v _t = __builtin_amdgcn_permlane16_swap((A), (B), false, false);   \
      (A) = _t[0]; (B) = _t[1]; }
#else
#define PLSWAP(A, B)                                                          \
    asm("s_nop 1\n\tv_permlane16_swap_b32 %0, %1" : "+v"(A), "+v"(B));
#endif

// DPP row-rotate-right by N within 16-lane rows (all lanes valid)
#define RORD(dst, src, N)                                                     \
    dst = (unsigned)__builtin_amdgcn_mov_dpp((int)(src), 0x120 + (N), 0xF, 0xF, false);

#if __has_builtin(__builtin_amdgcn_fdot2)
#define FDOT(g, W, a)                                                         \
    __builtin_amdgcn_fdot2(__builtin_bit_cast(half2v, (unsigned)(g)), (W), (a), false)
#else
__device__ inline float fdot2_emul(unsigned g, half2v w, float a) {
    half2v v = __builtin_bit_cast(half2v, g);
    a = fmaf((float)v[0], (float)w[0], a);
    return fmaf((float)v[1], (float)w[1], a);
}
#define FDOT(g, W, a) fdot2_emul((g), (W), (a))
#endif

// full 32-value gather from dword cc (f16 payload in low 16 bits)
#define GATHER(cc)                                                            \
    unsigned _r0 = (cc), _r1 = (cc);                                          \
    PLSWAP(_r0, _r1);                                                         \
    const unsigned _pt = psel ? _r0 : _r1;                                    \
    unsigned g0 = (_pt << 16) | ((cc) & 0xFFFFu);                             \
    unsigned g1, g2, g3, g4, g5, g6, g7, g8, g9, g10, g11, g12, g13, g14, g15;\
    RORD(g1, g0, 8)                                                           \
    RORD(g2, g0, 4)  RORD(g3, g1, 4)                                          \
    RORD(g4, g0, 2)  RORD(g5, g1, 2)  RORD(g6, g2, 2)  RORD(g7, g3, 2)        \
    RORD(g8, g0, 1)  RORD(g9, g1, 1)  RORD(g10, g2, 1) RORD(g11, g3, 1)       \
    RORD(g12, g4, 1) RORD(g13, g5, 1) RORD(g14, g6, 1) RORD(g15, g7, 1)

#define STEP(xval, uu)                                                        \
    {                                                                         \
        GATHER(c)                                                             \
        float a0 = (xval) + biasc, a1 = 0.f, a2 = 0.f, a3 = 0.f;              \
        a0 = FDOT(g0,  W0,  a0); a1 = FDOT(g1,  W1,  a1);                     \
        a2 = FDOT(g2,  W2,  a2); a3 = FDOT(g3,  W3,  a3);                     \
        a0 = FDOT(g4,  W4,  a0); a1 = FDOT(g5,  W5,  a1);                     \
        a2 = FDOT(g6,  W6,  a2); a3 = FDOT(g7,  W7,  a3);                     \
        a0 = FDOT(g8,  W8,  a0); a1 = FDOT(g9,  W9,  a1);                     \
        a2 = FDOT(g10, W10, a2); a3 = FDOT(g11, W11, a3);                     \
        a0 = FDOT(g12, W12, a0); a1 = FDOT(g13, W13, a1);                     \
        a2 = FDOT(g14, W14, a2); a3 = FDOT(g15, W15, a3);                     \
        const float a_ = (a0 + a1) + (a2 + a3);                               \
        const float p_ = __builtin_amdgcn_exp2f(a_);                          \
        rr = __builtin_amdgcn_rcpf(p_ + 1.0f);                                \
        const _Float16 rv_ = (_Float16)rr;                                    \
        c = (unsigned)__builtin_bit_cast(unsigned short, rv_);                \
        pbuf[half][uu][h] = fmaf(rr, w2o, wo);                                \
    }

// convert bf16x4 -> float4 (widening, exact)
#define CVT4(dst, src)                                                        \
    dst.x = (float)(src)[0]; dst.y = (float)(src)[1];                         \
    dst.z = (float)(src)[2]; dst.w = (float)(src)[3];

// phase-1 tile: global loads -> regs (issued ~1 block ahead of use)
#define TILE_LOAD(Xn, bb, lt)                                                 \
    do {                                                                      \
        const float* xp_ =                                                    \
            x + ((size_t)(b0 + (bb)) * Tc + (lt) * 16 + m) * Ic + q * 8;      \
        Xn##0 = ((const float4*)xp_)[0];                                      \
        Xn##1 = ((const float4*)xp_)[1];                                      \
        Xn##2 = ((const float4*)(xp_ + 32))[0];                               \
        Xn##3 = ((const float4*)(xp_ + 32))[1];                               \
    } while (0)

// phase-1 tile: MFMA + bias + bf16 pack + LDS store (R7-verified D layout:
// col=lane&15 -> h, row=q*4+reg -> t)
#define TILE_MFMA(Xn, bb, lt)                                                 \
    do {                                                                      \
        const bf16x8 A0_ = to_bf16x8(Xn##0, Xn##1);                           \
        const bf16x8 A1_ = to_bf16x8(Xn##2, Xn##3);                           \
        f32x4 ac0 = {0.f, 0.f, 0.f, 0.f};                                     \
        f32x4 ac1 = {0.f, 0.f, 0.f, 0.f};                                     \
        ac0 = __builtin_amdgcn_mfma_f32_16x16x32_bf16(A0_, Bf[0][0], ac0, 0, 0, 0); \
        ac0 = __builtin_amdgcn_mfma_f32_16x16x32_bf16(A1_, Bf[0][1], ac0, 0, 0, 0); \
        ac1 = __builtin_amdgcn_mfma_f32_16x16x32_bf16(A0_, Bf[1][0], ac1, 0, 0, 0); \
        ac1 = __builtin_amdgcn_mfma_f32_16x16x32_bf16(A1_, Bf[1][1], ac1, 0, 0, 0); \
        bf16x4 p0_, p1_;                                                      \
        p0_[0] = (__bf16)(ac0[0] + bias0); p0_[1] = (__bf16)(ac0[1] + bias0); \
        p0_[2] = (__bf16)(ac0[2] + bias0); p0_[3] = (__bf16)(ac0[3] + bias0); \
        p1_[0] = (__bf16)(ac1[0] + bias1); p1_[1] = (__bf16)(ac1[1] + bias1); \
        p1_[2] = (__bf16)(ac1[2] + bias1); p1_[3] = (__bf16)(ac1[3] + bias1); \
        *(bf16x4*)&xq[bb][m][(lt) * 16 + q * 4]      = p0_;                   \
        *(bf16x4*)&xq[bb][m + 16][(lt) * 16 + q * 4] = p1_;                   \
    } while (0)

__global__ __launch_bounds__(64) void fused_rnn_kernel(
    const float* __restrict__ x, const float* __restrict__ Wih,
    const float* __restrict__ bih, const float* __restrict__ h0,
    const float* __restrict__ Whh, const float* __restrict__ bhh,
    const float* __restrict__ Wout, const float* __restrict__ bout,
    float* __restrict__ out)
{
    __shared__ __bf16   xq[2][Hc][XP];    // 66048 B (scaled x-proj, bf16)
    __shared__ float    pbuf[2][16][34];  // 4352 B  -> ~69 KB, 2 blk/CU

    const int lane = threadIdx.x;
    const int half = lane >> 5;
    const int h    = lane & 31;
    const int m    = lane & 15;   // MFMA A-row / B-n index
    const int q    = lane >> 4;   // MFMA quad
    const int b0   = blockIdx.x * 2;

    // ---- init: Wih fragments (pre-scaled by LOG2E2) ----
    bf16x8 Bf[2][2];
#pragma unroll
    for (int nh = 0; nh < 2; ++nh)
#pragma unroll
        for (int kh = 0; kh < 2; ++kh) {
            const float* wp = Wih + (m + 16 * nh) * Ic + q * 8 + kh * 32;
            Bf[nh][kh] = to_bf16x8s(((const float4*)wp)[0],
                                    ((const float4*)wp)[1], LOG2E2);
        }
    const float bias0 = bih[m] * LOG2E2;
    const float bias1 = bih[m + 16] * LOG2E2;

    // ---- butterfly direction discovery + index simulation (payload = h) ---
    unsigned ch = (unsigned)h;
    unsigned d0_ = ch, d1_ = ch;
    PLSWAP(d0_, d1_);
    // whichever output holds h^16 on this lane is the "partner" register
    const bool psel = ((d0_ & 0xFFFFu) == (unsigned)(h ^ 16));
    const unsigned part0 = psel ? d0_ : d1_;
    unsigned s0 = (part0 << 16) | ch;
    unsigned s1, s2, s3, s4, s5, s6, s7, s8, s9, s10, s11, s12, s13, s14, s15;
    RORD(s1, s0, 8)
    RORD(s2, s0, 4)  RORD(s3, s1, 4)
    RORD(s4, s0, 2)  RORD(s5, s1, 2)  RORD(s6, s2, 2)  RORD(s7, s3, 2)
    RORD(s8, s0, 1)  RORD(s9, s1, 1)  RORD(s10, s2, 1) RORD(s11, s3, 1)
    RORD(s12, s4, 1) RORD(s13, s5, 1) RORD(s14, s6, 1) RORD(s15, s7, 1)

    // ---- recurrent weights: per-lane permuted, f16 pairs, scaled by cw ----
    const float cw = -2.0f * LOG2E2;
    const float* wr = Whh + h * Hc;
#define MKW(Wk, sk)                                                           \
    half2v Wk;                                                                \
    {                                                                         \
        const unsigned il_ = (sk) & 0xFFFFu, ih_ = (sk) >> 16;                \
        Wk[0] = (_Float16)(wr[il_] * cw);                                     \
        Wk[1] = (_Float16)(wr[ih_] * cw);                                     \
    }
    MKW(W0, s0)   MKW(W1, s1)   MKW(W2, s2)   MKW(W3, s3)
    MKW(W4, s4)   MKW(W5, s5)   MKW(W6, s6)   MKW(W7, s7)
    MKW(W8, s8)   MKW(W9, s9)   MKW(W10, s10) MKW(W11, s11)
    MKW(W12, s12) MKW(W13, s13) MKW(W14, s14) MKW(W15, s15)
#undef MKW

    // rsum for the affine fold: bias' = (bhh + rowsum(Whh)) * LOG2E2
    const float4* wrow = (const float4*)wr;
    const float4 t0 = wrow[0], t1 = wrow[1], t2 = wrow[2], t3 = wrow[3],
                 t4 = wrow[4], t5 = wrow[5], t6 = wrow[6], t7 = wrow[7];
    const float rsum =
        (((t0.x + t0.y) + (t0.z + t0.w)) + ((t1.x + t1.y) + (t1.z + t1.w))) +
        (((t2.x + t2.y) + (t2.z + t2.w)) + ((t3.x + t3.y) + (t3.z + t3.w))) +
        (((t4.x + t4.y) + (t4.z + t4.w)) + ((t5.x + t5.y) + (t5.z + t5.w))) +
        (((t6.x + t6.y) + (t6.z + t6.w)) + ((t7.x + t7.y) + (t7.z + t7.w)));
    const float biasc = (bhh[h] + rsum) * LOG2E2;
    const float wo  = Wout[h];
    const float w2o = -2.0f * wo;
    const float bo  = bout[0];

    // r = (1 - h)/2; h0 is the initial hidden state
    float rr = fmaf(-0.5f, h0[(size_t)(b0 + half) * Hc + h], 0.5f);
    {
        const _Float16 rv0 = (_Float16)rr;
        ch = (unsigned)__builtin_bit_cast(unsigned short, rv0);
    }
    unsigned c = ch;
    float* orow = out + (size_t)(b0 + half) * Tc;

    // ---- phase-1 prologue: tile-pairs 0,1 direct; stage pair-2 loads ------
    float4 Xa0, Xa1, Xa2, Xa3, Xb0, Xb1, Xb2, Xb3;
    TILE_LOAD(Xa, 0, 0);  TILE_LOAD(Xb, 1, 0);
    TILE_MFMA(Xa, 0, 0);  TILE_MFMA(Xb, 1, 0);
    TILE_LOAD(Xa, 0, 1);  TILE_LOAD(Xb, 1, 1);
    TILE_MFMA(Xa, 0, 1);  TILE_MFMA(Xb, 1, 1);
    TILE_LOAD(Xa, 0, 2);  TILE_LOAD(Xb, 1, 2);
    __syncthreads();   // single wave; drains LDS before scan reads

    // ---- scan ----
    const __bf16* xrow = &xq[half][h][0];

    bf16x4 r0 = *(const bf16x4*)(xrow + 0), r1 = *(const bf16x4*)(xrow + 4),
           r2 = *(const bf16x4*)(xrow + 8), r3 = *(const bf16x4*)(xrow + 12);
    float4 q0, q1, q2, q3;
    CVT4(q0, r0) CVT4(q1, r1) CVT4(q2, r2) CVT4(q3, r3)

#pragma unroll 1
    for (int tb = 0; tb < Tc / 16; ++tb) {
        const int tbn = (tb + 1 < Tc / 16) ? tb + 1 : tb;
        const __bf16* nx = xrow + tbn * 16;
        const bf16x4 m0 = *(const bf16x4*)(nx + 0),
                     m1 = *(const bf16x4*)(nx + 4),
                     m2 = *(const bf16x4*)(nx + 8),
                     m3 = *(const bf16x4*)(nx + 12);

        // fused phase-1: compute pair tb+2 (regs loaded last block), then
        // issue global loads for pair tb+3 (consumed next block).
        if (tb + 2 < Tc / 16) { TILE_MFMA(Xa, 0, tb + 2); TILE_MFMA(Xb, 1, tb + 2); }
        if (tb + 3 < Tc / 16) { TILE_LOAD(Xa, 0, tb + 3); TILE_LOAD(Xb, 1, tb + 3); }

        STEP(q0.x, 0)  STEP(q0.y, 1)  STEP(q0.z, 2)  STEP(q0.w, 3)
        STEP(q1.x, 4)  STEP(q1.y, 5)  STEP(q1.z, 6)  STEP(q1.w, 7)
        STEP(q2.x, 8)  STEP(q2.y, 9)  STEP(q2.z, 10) STEP(q2.w, 11)
        STEP(q3.x, 12) STEP(q3.y, 13) STEP(q3.z, 14) STEP(q3.w, 15)

        __builtin_amdgcn_wave_barrier();

        // both halves reduce their own batch; coalesced 16-wide stores
        if (h < 16) {
            const float2* pr = (const float2*)pbuf[half][h];
            float2 sa = pr[0], sb = pr[1];
#pragma unroll
            for (int mm = 2; mm < 16; mm += 2) {
                sa.x += pr[mm].x;     sa.y += pr[mm].y;
                sb.x += pr[mm + 1].x; sb.y += pr[mm + 1].y;
            }
            orow[tb * 16 + h] = ((sa.x + sb.x) + (sa.y + sb.y)) + bo;
        }
        __builtin_amdgcn_wave_barrier();

        CVT4(q0, m0) CVT4(q1, m1) CVT4(q2, m2) CVT4(q3, m3)
    }

    // h_last: [1, B, H] appended after outs [B, T, 1]; h = 1 - 2r
    out[(size_t)Bc * Tc + (size_t)(b0 + half) * Hc + h] = fmaf(-2.0f, rr, 1.0f);
}

extern "C" void kernel_launch(void* const* d_in, const int* in_sizes, int n_in,
                              void* d_out, int out_size, void* d_ws, size_t ws_size,
                              hipStream_t stream) {
    const float* x    = (const float*)d_in[0];
    const float* h0   = (const float*)d_in[1];
    const float* Wih  = (const float*)d_in[2];
    const float* bih  = (const float*)d_in[3];
    const float* Whh  = (const float*)d_in[4];
    const float* bhh  = (const float*)d_in[5];
    const float* Wout = (const float*)d_in[6];
    const float* bout = (const float*)d_in[7];
    float* out = (float*)d_out;

    fused_rnn_kernel<<<Bc / 2, 64, 0, stream>>>(x, Wih, bih, h0, Whh, bhh,
                                                Wout, bout, out);
}